// Round 13
// baseline (38.851 us; speedup 1.0000x reference)
//
#include <hip/hip_runtime.h>
#include <math.h>

// LightconvLayer: x (T,B,C) f32, weight (H,K) f32 -> out (T,B,C) f32
// out[t,b,c] = sum_k softmax(weight[c/64])[k] * x[t+k-30, b, c] (zero-pad left)
//
// R13: NO-LDS one-shot register-window streaming (vs R6-R12's LDS ring).
//  - thread <-> float2 channel pair; block = 256 thr = 512 ch (half of C)
//    for one (b, 8-row t-strip). 4096 blocks = 16k waves (4x R11 streams).
//  - per thread: 38 independent global_load_dwordx2 (rows tb-30..tb+7),
//    496 FMA, 8 dwordx2 stores. No LDS, no barriers, no inline-asm waits -
//    compiler schedules vmcnt; all indices compile-time (rule #20).
//  - read amplification 38/8 = 4.75x served by per-XCD L2 via strip-chunked
//    bijective swizzle: strip = (bx&7)*32 + (bx>>3)  (XCD k owns strips
//    [32k,32k+32); 16 (b,chalf) streams x 38-row window x 2 KB = 1.2 MB < 4 MB L2)
//  - VGPR budget: window 76 + taps 31 + addr ~10 + acc ~16 = ~133 < 170
//    (launch_bounds(256,3)); no spill (R3/R5 lesson: give allocator headroom).
#define T_LEN 2048
#define B_SZ  8
#define C_SZ  1024
#define NH    16
#define KW    31
#define HALO  (KW - 1)        // 30
#define TT    8               // t-rows per block
#define WIN   (TT + HALO)     // 38
#define NSTRIP (T_LEN / TT)   // 256 strips (%8==0 -> bijective XCD swizzle)
#define ROWSTRIDE (B_SZ * C_SZ)  // 8192 floats between t rows

template <bool CLIP>
__device__ __forceinline__ void conv_body(const float* __restrict__ xp,
                                          float* __restrict__ op,
                                          const float* __restrict__ wk,
                                          int tb) {
  // load window rows tb-30 .. tb+7 (38 independent dwordx2 loads)
  float2 xv[WIN];
#pragma unroll
  for (int i = 0; i < WIN; ++i) {
    const int t = tb - HALO + i;
    if (CLIP) {
      xv[i] = (t >= 0) ? *(const float2*)&xp[(size_t)t * ROWSTRIDE]
                       : make_float2(0.f, 0.f);
    } else {
      xv[i] = *(const float2*)&xp[(size_t)t * ROWSTRIDE];
    }
  }
  // 8 outputs, all indices compile-time
#pragma unroll
  for (int o = 0; o < TT; ++o) {
    float ax = 0.f, ay = 0.f;
#pragma unroll
    for (int k = 0; k < KW; ++k) {
      ax = fmaf(wk[k], xv[o + k].x, ax);
      ay = fmaf(wk[k], xv[o + k].y, ay);
    }
    *(float2*)&op[(size_t)o * ROWSTRIDE] = make_float2(ax, ay);
  }
}

__global__ __launch_bounds__(256, 3) void lightconv_kernel(
    const float* __restrict__ x, const float* __restrict__ weight,
    float* __restrict__ out) {
  const int tid = threadIdx.x;

  // strip-chunked XCD swizzle (bijective: 256 % 8 == 0); XCD k gets strips
  // [32k, 32k+32) so halo-sharing neighbors hit the same L2.
  const int bx    = blockIdx.x;
  const int strip = (bx & 7) * (NSTRIP / 8) + (bx >> 3);
  const int by    = blockIdx.y;
  const int b     = by >> 1;
  const int chalf = by & 1;
  const int tb    = strip * TT;
  const int c0    = chalf * (C_SZ / 2) + 2 * tid;  // this thread's channel pair

  // --- taps: per-thread head, softmax in VGPRs ---
  const int head = c0 >> 6;
  float wv[KW];
  float m = -1e30f;
#pragma unroll
  for (int k = 0; k < KW; ++k) {
    wv[k] = weight[head * KW + k];
    m = fmaxf(m, wv[k]);
  }
  float s = 0.f;
#pragma unroll
  for (int k = 0; k < KW; ++k) {
    wv[k] = expf(wv[k] - m);
    s += wv[k];
  }
  const float inv = 1.f / s;
  float wk[KW];
#pragma unroll
  for (int k = 0; k < KW; ++k) wk[k] = wv[k] * inv;

  const float* xp = x + (size_t)b * C_SZ + c0;
  float* op = out + ((size_t)tb * B_SZ + b) * C_SZ + c0;

  if (tb >= HALO) {
    conv_body<false>(xp, op, wk, tb);
  } else {
    conv_body<true>(xp, op, wk, tb);
  }
}

extern "C" void kernel_launch(void* const* d_in, const int* in_sizes, int n_in,
                              void* d_out, int out_size, void* d_ws, size_t ws_size,
                              hipStream_t stream) {
  const float* x = (const float*)d_in[0];      // (T,B,C) f32
  const float* w = (const float*)d_in[1];      // (H,K) f32
  float* out = (float*)d_out;                  // (T,B,C) f32
  (void)in_sizes; (void)n_in; (void)out_size; (void)d_ws; (void)ws_size;

  dim3 grid(NSTRIP, 2 * B_SZ);                 // (256, 16) = 4096 blocks
  dim3 block(256);
  lightconv_kernel<<<grid, block, 0, stream>>>(x, w, out);
}

// Round 14
// 36.705 us; speedup vs baseline: 1.0585x; 1.0585x over previous
//
#include <hip/hip_runtime.h>
#include <math.h>

// LightconvLayer: x (T,B,C) f32, weight (H,K) f32 -> out (T,B,C) f32
// out[t,b,c] = sum_k softmax(weight[c/64])[k] * x[t+k-30, b, c] (zero-pad left)
//
// R14 = R11 with ONE change: FULL-CHUNK PREFETCH (store-decoupled waits).
// gfx9 vmcnt is a single in-order queue for loads AND stores. R8-R12 issued
// staging loads AFTER previous tiles' stores, so every counted load-wait
// transitively waited on old HBM stores (slow completion) - the ~80% stall.
// Here ALL 32 staging loads issue in the prologue, before any store exists:
//  - ring = whole chunk: 64 rows x 128 ch x f32 = 32 KB, slots 1:1 (no wrap)
//  - per tile j: wait vmcnt(28+4j)  [newer-than-L(j) = (28-4j) staged loads
//    + 8j own stores; in-order retirement makes this EXACT for "L(j) done",
//    independent of store completion], 8x ds_read_b64, 496 FMA, 8 stores
//  - stores retire lazily; nothing ever waits on them (end-of-kernel drain)
#define T_LEN 2048
#define B_SZ  8
#define C_SZ  1024
#define NH    16
#define KW    31
#define HALO  (KW - 1)        // 30
#define TT    8
#define CHUNK 64              // rows per wave = ring size (no wraparound)
#define NTILE (CHUNK / TT)    // 8
#define WIN   (TT + HALO)     // 38
#define CGW   128             // channels per wave
#define ROWSTRIDE (B_SZ * C_SZ)  // 8192 floats between t rows

#define GLOBAL_AS(p) ((const __attribute__((address_space(1))) void*)(p))
#define LDS_AS(p)    ((__attribute__((address_space(3))) void*)(p))

__global__ __launch_bounds__(64, 3) void lightconv_kernel(
    const float* __restrict__ x, const float* __restrict__ weight,
    float* __restrict__ out) {
  __shared__ float ring[CHUNK][CGW];  // 32 KB, wave-private (1 wave/block)
  const int lane = threadIdx.x;

  const int cgrp = blockIdx.x & 7;   // 128-ch group (C/128 = 8)
  const int tc   = blockIdx.x >> 3;  // t-chunk 0..31
  const int b    = blockIdx.y;
  const int c0   = cgrp * CGW;
  const int tb   = tc * CHUNK;

  // --- taps: per-lane (2 heads per wave). load + softmax in VGPRs ---
  const int head = cgrp * 2 + (lane >> 5);
  float wv[KW];
  float m = -1e30f;
#pragma unroll
  for (int k = 0; k < KW; ++k) {
    wv[k] = weight[head * KW + k];
    m = fmaxf(m, wv[k]);
  }
  float s = 0.f;
#pragma unroll
  for (int k = 0; k < KW; ++k) {
    wv[k] = expf(wv[k] - m);
    s += wv[k];
  }
  const float inv = 1.f / s;
  float wk[KW];
#pragma unroll
  for (int k = 0; k < KW; ++k) wk[k] = wv[k] * inv;

  const float* xbase = x + (size_t)b * C_SZ + c0;
  const float* xch   = xbase + 2 * lane;  // per-lane channel pair base
  // staging offset: lane l -> row (l>>5), ch (l&31)*4 floats (16 B)
  const int lane_off = (lane >> 5) * ROWSTRIDE + (lane & 31) * 4;

  // --- prologue part 1: halo rows tb-30..tb-1 -> registers xv[0..29] ---
  float2 xv[WIN];
  if (tb == 0) {
#pragma unroll
    for (int i = 0; i < HALO; ++i) xv[i] = make_float2(0.f, 0.f);
  } else {
#pragma unroll
    for (int i = 0; i < HALO; ++i) {
      xv[i] = *(const float2*)&xch[(size_t)(tb - HALO + i) * ROWSTRIDE];
    }
  }
  __builtin_amdgcn_sched_barrier(0);  // keep halo loads older than staging

  // --- prologue part 2: stage the ENTIRE chunk (rows tb..tb+63 -> slots
  // 0..63), 32 x width-16 gload_lds (2 rows = 1 KB contiguous each).
  // No store has been issued yet -> no load-wait can depend on a store.
#pragma unroll
  for (int r2 = 0; r2 < CHUNK / 2; ++r2) {
    const float* gp = xbase + (size_t)(tb + 2 * r2) * ROWSTRIDE + lane_off;
    __builtin_amdgcn_global_load_lds(GLOBAL_AS(gp), LDS_AS(&ring[2 * r2][0]),
                                     16, 0, 0);
  }

  // --- 8 tiles, fully unrolled, waits count ONLY loads (exact, in-order) ---
#pragma unroll
  for (int j = 0; j < NTILE; ++j) {
    const int tstart = tb + j * TT;

    // newer-than-L(j) = (28 - 4j) staged loads + 8j own stores = 28 + 4j
    if (j == 0)       asm volatile("s_waitcnt vmcnt(28)" ::: "memory");
    else if (j == 1)  asm volatile("s_waitcnt vmcnt(32)" ::: "memory");
    else if (j == 2)  asm volatile("s_waitcnt vmcnt(36)" ::: "memory");
    else if (j == 3)  asm volatile("s_waitcnt vmcnt(40)" ::: "memory");
    else if (j == 4)  asm volatile("s_waitcnt vmcnt(44)" ::: "memory");
    else if (j == 5)  asm volatile("s_waitcnt vmcnt(48)" ::: "memory");
    else if (j == 6)  asm volatile("s_waitcnt vmcnt(52)" ::: "memory");
    else              asm volatile("s_waitcnt vmcnt(56)" ::: "memory");
    __builtin_amdgcn_sched_barrier(0);  // rule #18: pin ds_reads below

    // read tile j's 8 new rows (slots 8j..8j+7, compile-time imm offsets)
#pragma unroll
    for (int i = 0; i < TT; ++i) {
      const float2* rp = (const float2*)&ring[8 * j + i][0];
      xv[HALO + i] = rp[lane];
    }
    // compute + store 8 outputs (dwordx2); stores retire in background
    float* opb = out + ((size_t)tstart * B_SZ + b) * C_SZ + c0 + 2 * lane;
#pragma unroll
    for (int o = 0; o < TT; ++o) {
      float ax = 0.f, ay = 0.f;
#pragma unroll
      for (int k = 0; k < KW; ++k) {
        ax = fmaf(wk[k], xv[o + k].x, ax);
        ay = fmaf(wk[k], xv[o + k].y, ay);
      }
      *(float2*)&opb[(size_t)o * ROWSTRIDE] = make_float2(ax, ay);
    }
    // slide window by TT (full unroll -> pure register renaming)
#pragma unroll
    for (int i = 0; i < HALO; ++i) xv[i] = xv[i + TT];
  }
}

extern "C" void kernel_launch(void* const* d_in, const int* in_sizes, int n_in,
                              void* d_out, int out_size, void* d_ws, size_t ws_size,
                              hipStream_t stream) {
  const float* x = (const float*)d_in[0];      // (T,B,C) f32
  const float* w = (const float*)d_in[1];      // (H,K) f32
  float* out = (float*)d_out;                  // (T,B,C) f32
  (void)in_sizes; (void)n_in; (void)out_size; (void)d_ws; (void)ws_size;

  dim3 grid((C_SZ / CGW) * (T_LEN / CHUNK), B_SZ);  // (256, 8) = 2048 waves
  dim3 block(64);
  lightconv_kernel<<<grid, block, 0, stream>>>(x, w, out);
}